// Round 3
// baseline (22885.046 us; speedup 1.0000x reference)
//
#include <hip/hip_runtime.h>

// ---------------------------------------------------------------------------
// BidirRecurrentModel: 2-layer bidirectional GRU (both layers read raw x).
// ALL inputs/outputs are FLOAT32. Internally:
//   Phase 1: gx[b][l][t][g] = sum_d x[b,t,d]*Wx[l,g,d] + bx[l,g]
//            fp32 -> fp16 convert on the fly, f16 MFMA, gx stored fp16 in ws.
//   Phase 2: 128 independent chains (b,l,dir), sequential over T=2048.
//            256 threads/block (4 waves = 1 wave/EU -> full 512-VGPR budget).
//            Thread i owns unit i: 3 gate rows x 256 k as 384 fp16x2 VGPRs.
//            No partial reduction; ONE barrier/step (h2 + gxb double-buffered).
// ---------------------------------------------------------------------------

typedef _Float16 half8 __attribute__((ext_vector_type(8)));
typedef _Float16 half2_t __attribute__((ext_vector_type(2)));
typedef float floatx4 __attribute__((ext_vector_type(4)));

__device__ __forceinline__ float sigmoidf_fast(float x) {
    return 1.0f / (1.0f + __expf(-x));
}

__device__ __forceinline__ float tanh_fast(float x) {
    float ax = fabsf(x);
    float e = __expf(-2.0f * ax);
    float t = (1.0f - e) / (1.0f + e);
    return copysignf(t, x);
}

// ---------------------------------------------------------------------------
// Kernel 1: gx GEMM.  C[M=65536][N=1536] = x[M][256] * Wx[N][256]^T + bx[N]
// (unchanged from round 2 — ~280 us, revisit after the scan is fixed)
// ---------------------------------------------------------------------------
__global__ __launch_bounds__(256) void gemm_gx_kernel(
    const float* __restrict__ x,
    const float* __restrict__ Wx,
    const float* __restrict__ bx,
    _Float16* __restrict__ gx)
{
    __shared__ __align__(16) char lds[32768];
    _Float16* As = (_Float16*)lds;            // [4][128][8] fp16 (8 KB)
    _Float16* Bs = (_Float16*)(lds + 8192);   // [4][128][8] fp16 (8 KB)

    const int tid = threadIdx.x;
    const int m0 = blockIdx.x * 128;
    const int n0 = blockIdx.y * 128;
    const int wave = tid >> 6;
    const int lane = tid & 63;
    const int wm = wave & 1;
    const int wn = wave >> 1;
    const int frag = lane & 15;
    const int kg = lane >> 4;

    floatx4 acc[4][4];
#pragma unroll
    for (int a = 0; a < 4; ++a)
#pragma unroll
        for (int b = 0; b < 4; ++b)
            acc[a][b] = (floatx4){0.f, 0.f, 0.f, 0.f};

    for (int k0 = 0; k0 < 256; k0 += 32) {
        __syncthreads();
#pragma unroll
        for (int rep = 0; rep < 2; ++rep) {
            int idx = tid + rep * 256;   // 512 slots of 8 elems = 128x32 tile
            int row = idx >> 2;
            int kc = idx & 3;
            const float4* ap = (const float4*)(x + (size_t)(m0 + row) * 256 + k0 + kc * 8);
            const float4* bp = (const float4*)(Wx + (size_t)(n0 + row) * 256 + k0 + kc * 8);
            float4 a0 = ap[0], a1 = ap[1];
            float4 b0 = bp[0], b1 = bp[1];
            half8 av = {(_Float16)a0.x, (_Float16)a0.y, (_Float16)a0.z, (_Float16)a0.w,
                        (_Float16)a1.x, (_Float16)a1.y, (_Float16)a1.z, (_Float16)a1.w};
            half8 bv = {(_Float16)b0.x, (_Float16)b0.y, (_Float16)b0.z, (_Float16)b0.w,
                        (_Float16)b1.x, (_Float16)b1.y, (_Float16)b1.z, (_Float16)b1.w};
            *(half8*)(As + (kc * 128 + row) * 8) = av;
            *(half8*)(Bs + (kc * 128 + row) * 8) = bv;
        }
        __syncthreads();

        half8 af[4], bfr[4];
#pragma unroll
        for (int tm = 0; tm < 4; ++tm)
            af[tm] = *(const half8*)(As + (kg * 128 + wm * 64 + tm * 16 + frag) * 8);
#pragma unroll
        for (int tn = 0; tn < 4; ++tn)
            bfr[tn] = *(const half8*)(Bs + (kg * 128 + wn * 64 + tn * 16 + frag) * 8);
#pragma unroll
        for (int tm = 0; tm < 4; ++tm)
#pragma unroll
            for (int tn = 0; tn < 4; ++tn)
                acc[tm][tn] = __builtin_amdgcn_mfma_f32_16x16x32_f16(
                    af[tm], bfr[tn], acc[tm][tn], 0, 0, 0);
    }

    __syncthreads();
    _Float16* epi = (_Float16*)lds;  // [128][128]
#pragma unroll
    for (int tm = 0; tm < 4; ++tm) {
#pragma unroll
        for (int tn = 0; tn < 4; ++tn) {
            int col = wn * 64 + tn * 16 + frag;
            float bias = bx[n0 + col];
#pragma unroll
            for (int r = 0; r < 4; ++r) {
                int rowc = wm * 64 + tm * 16 + kg * 4 + r;  // C/D: col=lane&15, row=quad*4+reg
                epi[rowc * 128 + col] = (_Float16)(acc[tm][tn][r] + bias);
            }
        }
    }
    __syncthreads();

    int row = tid >> 1;
    int hs = tid & 1;
    int gm = m0 + row;
    int bb = gm >> 11;          // batch
    int tt = gm & 2047;         // time
    int l = n0 / 768;           // 768 % 128 == 0, block never crosses l
    int g0 = n0 - l * 768 + hs * 64;
    size_t oidx = (((size_t)bb * 2 + l) * 2048 + tt) * 768 + g0;
    const uint4* s = (const uint4*)(epi + row * 128 + hs * 64);
    uint4* d = (uint4*)(gx + oidx);
#pragma unroll
    for (int j = 0; j < 8; ++j) d[j] = s[j];
}

// ---------------------------------------------------------------------------
// Kernel 2: the recurrence. One block per chain (b, l, dir); 128 blocks.
// 256 threads = 4 waves = 1 wave/EU => 512-VGPR budget (the round-2 spill
// fix). Thread i owns unit i fully: 3x128 half2 weight VGPRs, full-K dots,
// no partial exchange. One __syncthreads per step; h2 and gxb double-buffered.
// ---------------------------------------------------------------------------
__global__ __launch_bounds__(256, 1) void gru_scan_kernel(
    const float* __restrict__ Wh,
    const float* __restrict__ bh,
    const _Float16* __restrict__ gx,
    float* __restrict__ out)
{
    const int c = blockIdx.x;
    const int b = c & 31;
    const int l = (c >> 5) & 1;
    const int dir = c >> 6;
    const int i = threadIdx.x;   // 0..255, output unit

    __shared__ __align__(16) _Float16 h2[2][256];   // double-buffered h (fp16)
    __shared__ __align__(16) _Float16 gxb[2][768];  // double-buffered gx_t

    // --- one-time: load Wh rows {i, 256+i, 512+i}, fp32 -> fp16x2 regs ---
    half2_t wr[128], wz[128], wn_[128];
    {
        const float2* pr = (const float2*)(Wh + ((size_t)l * 768 + i) * 256);
        const float2* pz = (const float2*)(Wh + ((size_t)l * 768 + 256 + i) * 256);
        const float2* pn = (const float2*)(Wh + ((size_t)l * 768 + 512 + i) * 256);
#pragma unroll 16
        for (int j = 0; j < 128; ++j) {
            float2 a = pr[j], bb2 = pz[j], cc = pn[j];
            wr[j]  = (half2_t){(_Float16)a.x, (_Float16)a.y};
            wz[j]  = (half2_t){(_Float16)bb2.x, (_Float16)bb2.y};
            wn_[j] = (half2_t){(_Float16)cc.x, (_Float16)cc.y};
        }
    }

    const float bhr = bh[l * 768 + i];
    const float bhz = bh[l * 768 + 256 + i];
    const float bhn = bh[l * 768 + 512 + i];

    const _Float16* gxrow = gx + (size_t)(b * 2 + l) * 2048 * 768;
    // out[b][t*2+l][dir*256+i], out shape (32, 4096, 512)
    float* outp = out + (size_t)b * 2097152 + (size_t)l * 512 + dir * 256 + i;

    h2[0][i] = (_Float16)0.f;
    {
        int t0 = dir ? 2047 : 0;
        if (i < 96) ((uint4*)gxb[0])[i] = ((const uint4*)(gxrow + (size_t)t0 * 768))[i];
    }
    __syncthreads();

    float hreg = 0.f;

    for (int s = 0; s < 2048; ++s) {
        const int t = dir ? (2047 - s) : s;
        const int sn = (s < 2047) ? (s + 1) : s;
        const int tn = dir ? (2047 - sn) : sn;

        // prefetch next step's gx row (16B/lane x 96 lanes); latency hidden
        // behind the dot phase. s=2047: re-loads same row (benign).
        uint4 pf;
        if (i < 96) pf = ((const uint4*)(gxrow + (size_t)tn * 768))[i];

        // --- dot phase: 3 gates x 256 k = 384 v_dot2, all operands in VGPRs,
        //     h via wave-uniform (broadcast) LDS reads ---
        float ar = 0.f, az = 0.f, an = 0.f;
        const half2_t* hp = (const half2_t*)h2[s & 1];
#pragma unroll
        for (int j = 0; j < 128; ++j) {
            half2_t hv = hp[j];
            ar = __builtin_amdgcn_fdot2(wr[j], hv, ar, false);
            az = __builtin_amdgcn_fdot2(wz[j], hv, az, false);
            an = __builtin_amdgcn_fdot2(wn_[j], hv, an, false);
        }

        // --- gate math (every thread owns its unit; no reduction) ---
        const _Float16* gxc = gxb[s & 1];
        float xr = (float)gxc[i];
        float xz = (float)gxc[256 + i];
        float xn = (float)gxc[512 + i];
        float r = sigmoidf_fast(xr + ar + bhr);
        float z = sigmoidf_fast(xz + az + bhz);
        float n = tanh_fast(xn + r * (an + bhn));
        float hnew = (1.f - z) * n + z * hreg;
        hreg = hnew;

        outp[(size_t)t * 1024] = hnew;
        h2[(s + 1) & 1][i] = (_Float16)hnew;
        if (i < 96) ((uint4*)gxb[sn & 1])[i] = pf;

        __syncthreads();   // the ONLY barrier per step
    }
}

// ---------------------------------------------------------------------------
extern "C" void kernel_launch(void* const* d_in, const int* in_sizes, int n_in,
                              void* d_out, int out_size, void* d_ws, size_t ws_size,
                              hipStream_t stream) {
    const float* x  = (const float*)d_in[0];  // (32,2048,256) fp32
    const float* Wx = (const float*)d_in[1];  // (2,768,256)  fp32
    const float* Wh = (const float*)d_in[2];  // (2,768,256)  fp32
    const float* bx = (const float*)d_in[3];  // (2,768)      fp32
    const float* bh = (const float*)d_in[4];  // (2,768)      fp32
    float* out = (float*)d_out;               // (32,4096,512) fp32
    _Float16* gxbuf = (_Float16*)d_ws;        // 100,663,296 fp16 = 201.3 MB

    // Phase 1: gx = x @ Wx^T + bx  (layout [b][l][t][768], fp16)
    gemm_gx_kernel<<<dim3(512, 12), 256, 0, stream>>>(x, Wx, bx, gxbuf);

    // Phase 2: 128 independent (b, l, dir) GRU chains
    gru_scan_kernel<<<dim3(128), 256, 0, stream>>>(Wh, bh, gxbuf, out);
}